// Round 14
// baseline (80.066 us; speedup 1.0000x reference)
//
#include <hip/hip_runtime.h>

#define B_ 8
#define S_ 2048
#define D_ 256

typedef _Float16 f16;
typedef f16 f16x2 __attribute__((ext_vector_type(2)));
typedef f16 f16x8 __attribute__((ext_vector_type(8)));
typedef float f32x16 __attribute__((ext_vector_type(16)));
typedef unsigned int u32;
typedef u32 u32x4 __attribute__((ext_vector_type(4)));

typedef const __attribute__((address_space(1))) unsigned int* gptr_t;
typedef __attribute__((address_space(3))) unsigned int* lptr_t;

__device__ __forceinline__ void gload_lds16(const void* g, void* l) {
  __builtin_amdgcn_global_load_lds((gptr_t)(unsigned long long)g,
                                   (lptr_t)(unsigned long long)l, 16, 0, 0);
}

__device__ __forceinline__ u32 packf16(float a, float b) {
  f16x2 t; t[0] = (f16)a; t[1] = (f16)b;
  return __builtin_bit_cast(u32, t);
}

// acc (lane-dim col, crow rows) -> lane holds its lane-row, crow-contiguous:
// s0 = crow 0..15 (16B at +hi*8), s1 = crow 16..31 (+16+hi*8).
__device__ __forceinline__ void pack16(const f32x16& p, int hi, u32x4& o0, u32x4& o1) {
#pragma unroll
  for (int c2 = 0; c2 < 2; ++c2) {
    u32 a1 = packf16(p[8 * c2 + 0], p[8 * c2 + 1]);
    u32 a2 = packf16(p[8 * c2 + 2], p[8 * c2 + 3]);
    u32 b1 = packf16(p[8 * c2 + 4], p[8 * c2 + 5]);
    u32 b2 = packf16(p[8 * c2 + 6], p[8 * c2 + 7]);
    u32 xa1 = __shfl_xor(a1, 32), xa2 = __shfl_xor(a2, 32);
    u32 xb1 = __shfl_xor(b1, 32), xb2 = __shfl_xor(b2, 32);
    u32x4 f;
    f[0] = hi ? xb1 : a1;
    f[1] = hi ? xb2 : a2;
    f[2] = hi ? b1 : xa1;
    f[3] = hi ? b2 : xa2;
    if (c2) o1 = f; else o0 = f;
  }
}

#define SC2F 0.09016844f   // log2(e)/16
#define NMAXR 20.0f        // >= max row norm (chi2_256 max ~ sqrt(397))

// ---- fused prep: xh (f16), n2 (row norms^2), Wt[128 j][256 d] -------------
__global__ void prep(const float* __restrict__ x, const float* __restrict__ Wm,
                     const float* __restrict__ Wl, f16* __restrict__ xh,
                     float* __restrict__ n2, f16* __restrict__ Wt) {
  __shared__ f16 tile[64][264];
  const int bid = blockIdx.x;
  const int t = threadIdx.x;          // 256
  if (bid < 256) {
    const int b = bid >> 5, st = bid & 31;
    const int s0 = st * 64;
    const float* xb = x + ((size_t)(b * S_ + s0)) * D_;
    f16* xhb = xh + ((size_t)(b * S_ + s0)) * D_;
#pragma unroll
    for (int it = 0; it < 16; ++it) {
      int flat = it * 256 + t;
      int r = flat >> 6, c4 = flat & 63;
      float4 v = *reinterpret_cast<const float4*>(xb + r * 256 + c4 * 4);
      f16 h0 = (f16)v.x, h1 = (f16)v.y, h2 = (f16)v.z, h3 = (f16)v.w;
      f16x2 p0 = {h0, h1}, p1 = {h2, h3};
      uint2 wv; wv.x = __builtin_bit_cast(u32, p0); wv.y = __builtin_bit_cast(u32, p1);
      *reinterpret_cast<uint2*>(xhb + r * 256 + c4 * 4) = wv;
      tile[r][c4 * 4 + 0] = h0; tile[r][c4 * 4 + 1] = h1;
      tile[r][c4 * 4 + 2] = h2; tile[r][c4 * 4 + 3] = h3;
    }
    __syncthreads();
    {
      int r = t >> 2, qd = t & 3;
      float s = 0.0f;
#pragma unroll
      for (int i = 0; i < 8; ++i) {
        f16x8 v = *reinterpret_cast<const f16x8*>(&tile[r][qd * 64 + i * 8]);
#pragma unroll
        for (int u = 0; u < 8; ++u) { float f = (float)v[u]; s += f * f; }
      }
      s += __shfl_xor(s, 1); s += __shfl_xor(s, 2);
      if (qd == 0) n2[b * S_ + s0 + r] = s;
    }
  } else {
    int idx = (bid - 256) * 1024 + t * 4;
    int j = idx >> 8, d = idx & 255;
#pragma unroll
    for (int k2 = 0; k2 < 4; ++k2) {
      float v = (j < 64) ? Wm[(d + k2) * 64 + j] : Wl[(d + k2) * 64 + (j - 64)];
      Wt[idx + k2] = (f16)v;
    }
  }
}

// ---- xw: XWt[b][j 128][s 2048] = (xh @ Wt^T)^T, f16 -----------------------
__launch_bounds__(256)
__global__ void xw_kern(const f16* __restrict__ xh, const f16* __restrict__ Wt,
                        f16* __restrict__ XWt) {
  __shared__ f16 Ax[2][4096];   // [buf][64 s][64 d]
  __shared__ f16 Ww[2][8192];   // [buf][128 j][64 d]
  const int idx = blockIdx.x;
  const int b = idx & 7;
  const int sb = (idx >> 3) * 64;
  const int tid = threadIdx.x, lane = tid & 63, w = tid >> 6;   // w = wj
  const int l31 = lane & 31, hi = lane >> 5;
  const f16* xb = xh + (size_t)b * S_ * D_;

#define XW_STAGE(st, pp)                                                       \
  {                                                                            \
    _Pragma("unroll") for (int i = 0; i < 2; ++i) {                            \
      int ch = i * 256 + tid; int r = ch >> 3, c = ch & 7;                     \
      int csrc = c ^ (r & 7);                                                  \
      gload_lds16(xb + (size_t)(sb + r) * 256 + ((st) * 64) + csrc * 8,        \
                  &Ax[(pp)][0] + ch * 8);                                      \
    }                                                                          \
    _Pragma("unroll") for (int i = 0; i < 4; ++i) {                            \
      int ch = i * 256 + tid; int r = ch >> 3, c = ch & 7;                     \
      int csrc = c ^ (r & 7);                                                  \
      gload_lds16(Wt + (size_t)r * 256 + ((st) * 64) + csrc * 8,               \
                  &Ww[(pp)][0] + ch * 8);                                      \
    }                                                                          \
  }

  f32x16 acc[2];
#pragma unroll
  for (int i = 0; i < 2; ++i)
#pragma unroll
    for (int e = 0; e < 16; ++e) acc[i][e] = 0.0f;

  XW_STAGE(0, 0);
  __syncthreads();
#pragma unroll
  for (int t = 0; t < 4; ++t) {
    const int p = t & 1;
    if (t < 3) XW_STAGE(t + 1, p ^ 1);
#pragma unroll
    for (int kc = 0; kc < 4; ++kc) {
      int cc = ((2 * kc + hi) ^ (l31 & 7)) * 8;
      f16x8 bf = *reinterpret_cast<const f16x8*>(&Ww[p][(w * 32 + l31) * 64 + cc]);
#pragma unroll
      for (int mi = 0; mi < 2; ++mi) {
        f16x8 af = *reinterpret_cast<const f16x8*>(&Ax[p][(mi * 32 + l31) * 64 + cc]);
        acc[mi] = __builtin_amdgcn_mfma_f32_32x32x16_f16(af, bf, acc[mi], 0, 0, 0);
      }
    }
    __syncthreads();
  }
#undef XW_STAGE

  const int j = w * 32 + l31;
  f16* dst = XWt + ((size_t)b * 128 + j) * 2048;
#pragma unroll
  for (int mi = 0; mi < 2; ++mi) {
    u32x4 s0, s1;
    pack16(acc[mi], hi, s0, s1);
    *reinterpret_cast<u32x4*>(dst + sb + mi * 32 + hi * 8) = s0;
    *reinterpret_cast<u32x4*>(dst + sb + mi * 32 + 16 + hi * 8) = s1;
  }
}

// ------ GEMM1 (triangular, acc[2][2]): S-tile once, P[q,kv], P[kv,q], Lp ---
// tile 128q x 128kv, K=256 in 4 steps of 64; 256 thr = 4 waves (wq2 x wk2)
// wave: 64q x 64kv acc[2][2] -> 1 ds_read per MFMA
__launch_bounds__(256, 2)
__global__ void gemm1_kern(const f16* __restrict__ xh, const float* __restrict__ n2,
                           f16* __restrict__ P, float* __restrict__ Lp,
                           int b0, int bm, int bsh) {
  __shared__ __align__(16) char smem[65536];
  f16* Aq = (f16*)smem;            // 2 bufs x [128 q][64 d]
  f16* Bk = (f16*)(smem + 32768);  // 2 bufs x [128 kv][64 d]
  const int idx = blockIdx.x;
  const int bl = idx & bm;
  int tdec = idx >> bsh;           // 0..135
  int qt = 0;
#pragma unroll 1
  while (tdec >= 16 - qt) { tdec -= 16 - qt; ++qt; }
  const int kt = qt + tdec;
  const int b = b0 + bl;
  const int qb = qt * 128, kb = kt * 128;
  const int tid = threadIdx.x, lane = tid & 63, w = tid >> 6;
  const int l31 = lane & 31, hi = lane >> 5;
  const int wq = w >> 1, wk = w & 1;
  const f16* xb = xh + (size_t)b * S_ * D_;

#define G1_STAGE(st, pp)                                                       \
  { _Pragma("unroll") for (int i = 0; i < 8; ++i) {                            \
      int flat = (w * 8 + i) * 64 + lane;                                      \
      bool isB = flat >= 1024;                                                 \
      int ch = flat & 1023;                                                    \
      int r = ch >> 3, c = ch & 7;                                             \
      int csrc = c ^ (r & 7);                                                  \
      const f16* src = xb + (size_t)((isB ? kb : qb) + r) * 256 +              \
                       ((st) * 64) + csrc * 8;                                 \
      f16* dst = (isB ? Bk : Aq) + ((pp) * 8192) + ch * 8;                     \
      gload_lds16(src, dst);                                                   \
    } }

  f32x16 acc[2][2];
#pragma unroll
  for (int i = 0; i < 2; ++i)
#pragma unroll
    for (int j = 0; j < 2; ++j)
#pragma unroll
      for (int e = 0; e < 16; ++e) acc[i][j][e] = 0.0f;

  G1_STAGE(0, 0);
  __syncthreads();
#pragma unroll
  for (int t = 0; t < 4; ++t) {
    const int p = t & 1;
    if (t < 3) G1_STAGE(t + 1, p ^ 1);
#pragma unroll
    for (int kc = 0; kc < 4; ++kc) {
      int cc = ((2 * kc + hi) ^ (l31 & 7)) * 8;
      f16x8 af[2], bf[2];
#pragma unroll
      for (int mi = 0; mi < 2; ++mi)
        af[mi] = *reinterpret_cast<const f16x8*>(
            Bk + p * 8192 + (wk * 64 + mi * 32 + l31) * 64 + cc);
#pragma unroll
      for (int ni = 0; ni < 2; ++ni)
        bf[ni] = *reinterpret_cast<const f16x8*>(
            Aq + p * 8192 + (wq * 64 + ni * 32 + l31) * 64 + cc);
#pragma unroll
      for (int mi = 0; mi < 2; ++mi)
#pragma unroll
        for (int ni = 0; ni < 2; ++ni)
          acc[mi][ni] = __builtin_amdgcn_mfma_f32_32x32x16_f16(
              af[mi], bf[ni], acc[mi][ni], 0, 0, 0);
    }
    __syncthreads();
  }
#undef G1_STAGE

  // ---- raw S into LDS (f32, XOR-swizzled cols) for the transposed store ----
  float* raw = (float*)smem;   // [128 kv][128 q]
  if (kt != qt) {
#pragma unroll
    for (int mi = 0; mi < 2; ++mi)
#pragma unroll
      for (int ni = 0; ni < 2; ++ni)
#pragma unroll
        for (int j = 0; j < 16; ++j) {
          int kvloc = wk * 64 + mi * 32 + (j & 3) + 8 * (j >> 2) + 4 * hi;
          int qloc = wq * 64 + ni * 32 + l31;
          raw[kvloc * 128 + (qloc ^ ((kvloc & 7) << 2))] = acc[mi][ni][j];
        }
  }

  // ---- register epilogue: P[q][kv], shift R_q, row-sum partials ----
  float r2[2], lsum[2];
  int qrow[2];
#pragma unroll
  for (int ni = 0; ni < 2; ++ni) {
    qrow[ni] = qb + wq * 64 + ni * 32 + l31;
    r2[ni] = sqrtf(n2[b * S_ + qrow[ni]]) * (NMAXR * SC2F);
    lsum[ni] = 0.0f;
  }
#pragma unroll
  for (int mi = 0; mi < 2; ++mi)
#pragma unroll
    for (int ni = 0; ni < 2; ++ni)
#pragma unroll
      for (int j = 0; j < 16; ++j) {
        float v = exp2f(acc[mi][ni][j] * SC2F - r2[ni]);
        acc[mi][ni][j] = v;
        lsum[ni] += v;
      }
#pragma unroll
  for (int ni = 0; ni < 2; ++ni) lsum[ni] += __shfl_xor(lsum[ni], 32);

#pragma unroll
  for (int mi = 0; mi < 2; ++mi) {
    const int colb = kb + wk * 64 + mi * 32;
#pragma unroll
    for (int ni = 0; ni < 2; ++ni) {
      u32x4 s0, s1;
      pack16(acc[mi][ni], hi, s0, s1);
      size_t rowp = (size_t)(bl * S_ + qrow[ni]) * 2048;
      *reinterpret_cast<u32x4*>(P + rowp + colb + hi * 8) = s0;
      *reinterpret_cast<u32x4*>(P + rowp + colb + 16 + hi * 8) = s1;
    }
  }

  // ---- transposed epilogue: P[kv][q], shift R_kv, col-sum partials ----
  if (kt != qt) {
    __syncthreads();
    const int kvr = tid >> 1;          // 0..127
    const int qh = (tid & 1) * 64;
    float r2kv = sqrtf(n2[b * S_ + kb + kvr]) * (NMAXR * SC2F);
    u32 ow[32];
    float tsum = 0.0f;
#pragma unroll
    for (int c16 = 0; c16 < 16; ++c16) {
      int qs = qh + c16 * 4;
      float4 v = *reinterpret_cast<const float4*>(
          &raw[kvr * 128 + (qs ^ ((kvr & 7) << 2))]);
      float e0 = exp2f(v.x * SC2F - r2kv), e1 = exp2f(v.y * SC2F - r2kv);
      float e2 = exp2f(v.z * SC2F - r2kv), e3 = exp2f(v.w * SC2F - r2kv);
      tsum += (e0 + e1) + (e2 + e3);
      ow[c16 * 2 + 0] = packf16(e0, e1);
      ow[c16 * 2 + 1] = packf16(e2, e3);
    }
    size_t rowp = (size_t)(bl * S_ + kb + kvr) * 2048;
#pragma unroll
    for (int sseg = 0; sseg < 8; ++sseg) {
      u32x4 sv;
      sv[0] = ow[sseg * 4 + 0]; sv[1] = ow[sseg * 4 + 1];
      sv[2] = ow[sseg * 4 + 2]; sv[3] = ow[sseg * 4 + 3];
      *reinterpret_cast<u32x4*>(P + rowp + qb + qh + sseg * 8) = sv;
    }
    tsum += __shfl_xor(tsum, 1);
    if ((tid & 1) == 0)
      Lp[(size_t)(bl * 16 + qt) * 2048 + kb + kvr] = tsum;
  }

  // ---- Lred reduce for register-path partials ----
  __syncthreads();
  float* Lred = (float*)smem;   // [128 q][2 wk]
  if (hi == 0) {
#pragma unroll
    for (int ni = 0; ni < 2; ++ni)
      Lred[(wq * 64 + ni * 32 + l31) * 2 + wk] = lsum[ni];
  }
  __syncthreads();
  if (tid < 128)
    Lp[(size_t)(bl * 16 + kt) * 2048 + qb + tid] = Lred[tid * 2] + Lred[tid * 2 + 1];
}

// ------ GEMM2P (split-K=4, acc[2][2]): Yp[ks] = (P @ XWt^T)/L over K/4 -----
// tile 128q x 128j, K/4=512 in 8 steps of 64; 256 thr = 4 waves (wq2 x wc2)
// grid bpp*64: bl fastest, qt (16), ks (4) top
__launch_bounds__(256, 2)
__global__ void gemm2p_kern(const f16* __restrict__ P, const f16* __restrict__ XWt,
                            float* __restrict__ Yp, int b0, int bm_, int bsh,
                            int kso) {
  __shared__ f16 Pq[2][8192];   // [buf][128 q][64 kv]
  __shared__ f16 Xw[2][8192];   // [buf][128 j][64 kv]
  const int idx = blockIdx.x;
  const int bl = idx & bm_;
  const int qt = (idx >> bsh) & 15;
  const int ks = idx >> (bsh + 4);   // 0..3
  const int b = b0 + bl;
  const int qb = qt * 128;
  const int kcol0 = ks * 512;
  const int tid = threadIdx.x, lane = tid & 63, w = tid >> 6;
  const int l31 = lane & 31, hi = lane >> 5;
  const int wq = w >> 1, wc = w & 1;
  const f16* xwb = XWt + (size_t)b * 128 * 2048;

#define GP_STAGE(tt, pp)                                                       \
  { _Pragma("unroll") for (int i = 0; i < 8; ++i) {                            \
      int flat = (w * 8 + i) * 64 + lane;                                      \
      bool isX = flat >= 1024;                                                 \
      int ch = flat & 1023;                                                    \
      int r = ch >> 3, c = ch & 7;                                             \
      int csrc = c ^ (r & 7);                                                  \
      const f16* src = isX                                                     \
          ? xwb + (size_t)r * 2048 + kcol0 + ((tt) * 64) + csrc * 8            \
          : P + (size_t)(bl * S_ + qb + r) * 2048 + kcol0 + ((tt) * 64) + csrc * 8; \
      f16* dst = (isX ? &Xw[(pp)][0] : &Pq[(pp)][0]) + ch * 8;                 \
      gload_lds16(src, dst);                                                   \
    } }

  f32x16 acc[2][2];
#pragma unroll
  for (int i = 0; i < 2; ++i)
#pragma unroll
    for (int j = 0; j < 2; ++j)
#pragma unroll
      for (int e = 0; e < 16; ++e) acc[i][j][e] = 0.0f;

  GP_STAGE(0, 0);
  __syncthreads();
#pragma unroll 1
  for (int t = 0; t < 8; ++t) {
    const int p = t & 1;
    if (t < 7) GP_STAGE(t + 1, p ^ 1);
#pragma unroll
    for (int kc = 0; kc < 4; ++kc) {
      int cc = ((2 * kc + hi) ^ (l31 & 7)) * 8;
      f16x8 af[2], bf[2];
#pragma unroll
      for (int mi = 0; mi < 2; ++mi)
        af[mi] = *reinterpret_cast<const f16x8*>(
            &Xw[p][(wc * 64 + mi * 32 + l31) * 64 + cc]);
#pragma unroll
      for (int ni = 0; ni < 2; ++ni)
        bf[ni] = *reinterpret_cast<const f16x8*>(
            &Pq[p][(wq * 64 + ni * 32 + l31) * 64 + cc]);
#pragma unroll
      for (int mi = 0; mi < 2; ++mi)
#pragma unroll
        for (int ni = 0; ni < 2; ++ni)
          acc[mi][ni] = __builtin_amdgcn_mfma_f32_32x32x16_f16(
              af[mi], bf[ni], acc[mi][ni], 0, 0, 0);
    }
    __syncthreads();
  }
#undef GP_STAGE

  // epilogue: store f32 partials (no rL here; reduce applies 1/L via Lsum)
#pragma unroll
  for (int ni = 0; ni < 2; ++ni) {
    const int q = qb + wq * 64 + ni * 32 + l31;
    float* dst = Yp + ((size_t)ks * kso + (size_t)bl * S_ + q) * 128;
#pragma unroll
    for (int mi = 0; mi < 2; ++mi)
#pragma unroll
      for (int jg = 0; jg < 4; ++jg) {
        int cb = wc * 64 + mi * 32 + 8 * jg + 4 * hi;
        float4 v;
        v.x = acc[mi][ni][jg * 4 + 0];
        v.y = acc[mi][ni][jg * 4 + 1];
        v.z = acc[mi][ni][jg * 4 + 2];
        v.w = acc[mi][ni][jg * 4 + 3];
        *reinterpret_cast<float4*>(dst + cb) = v;
      }
  }
}

// ------ reduce: out = reparam( (sum_ks Yp)/L + bias ) ----------------------
// grid bpp*64: block = 32 rows x 64 paired cols; thread = 1 row x 8 cols
__launch_bounds__(256)
__global__ void reduce_kern(const float* __restrict__ Yp, const float* __restrict__ Lp,
                            const float* __restrict__ bm, const float* __restrict__ bl_,
                            const float* __restrict__ eps, float* __restrict__ out,
                            int b0, int kso) {
  const int t = threadIdx.x;
  const int rowp = blockIdx.x * 32 + (t >> 3);   // 0..kso-1
  const int j0 = (t & 7) * 8;
  const int grow = b0 * S_ + rowp;
  const int bl = rowp >> 11, q = rowp & 2047;
  float L = 0.0f;
#pragma unroll
  for (int kt = 0; kt < 16; ++kt) L += Lp[(size_t)(bl * 16 + kt) * 2048 + q];
  float rL = 1.0f / L;
  float mv[8], lv[8];
#pragma unroll
  for (int i = 0; i < 8; ++i) { mv[i] = 0.0f; lv[i] = 0.0f; }
#pragma unroll
  for (int k = 0; k < 4; ++k) {
    const float* y = Yp + ((size_t)k * kso + rowp) * 128;
#pragma unroll
    for (int i = 0; i < 2; ++i) {
      float4 a = *reinterpret_cast<const float4*>(y + j0 + i * 4);
      float4 c = *reinterpret_cast<const float4*>(y + 64 + j0 + i * 4);
      mv[i*4+0] += a.x; mv[i*4+1] += a.y; mv[i*4+2] += a.z; mv[i*4+3] += a.w;
      lv[i*4+0] += c.x; lv[i*4+1] += c.y; lv[i*4+2] += c.z; lv[i*4+3] += c.w;
    }
  }
  float ev[8];
#pragma unroll
  for (int i = 0; i < 2; ++i) {
    float4 e = *reinterpret_cast<const float4*>(eps + (size_t)grow * 64 + j0 + i * 4);
    ev[i*4+0] = e.x; ev[i*4+1] = e.y; ev[i*4+2] = e.z; ev[i*4+3] = e.w;
  }
  float om[8], ol[8], oa[8];
#pragma unroll
  for (int i = 0; i < 8; ++i) {
    float m = mv[i] * rL + bm[j0 + i];
    float l = lv[i] * rL + bl_[j0 + i];
    om[i] = m;
    ol[i] = l;
    oa[i] = m + exp2f(0.7213475204f * l) * ev[i];
  }
  float* o0 = out + (size_t)grow * 64 + j0;
#pragma unroll
  for (int i = 0; i < 2; ++i) {
    *reinterpret_cast<float4*>(o0 + i * 4) = *reinterpret_cast<float4*>(&om[i * 4]);
    *reinterpret_cast<float4*>(o0 + 1048576 + i * 4) = *reinterpret_cast<float4*>(&ol[i * 4]);
    *reinterpret_cast<float4*>(o0 + 2097152 + i * 4) = *reinterpret_cast<float4*>(&oa[i * 4]);
  }
}

extern "C" void kernel_launch(void* const* d_in, const int* in_sizes, int n_in,
                              void* d_out, int out_size, void* d_ws, size_t ws_size,
                              hipStream_t stream) {
  (void)in_sizes; (void)n_in; (void)out_size;
  const float* x   = (const float*)d_in[0];
  const float* Wm  = (const float*)d_in[1];
  const float* bmv = (const float*)d_in[2];
  const float* Wl  = (const float*)d_in[3];
  const float* blv = (const float*)d_in[4];
  const float* ep  = (const float*)d_in[5];
  float* out = (float*)d_out;

  char* ws = (char*)d_ws;
  f16*   xh   = (f16*)(ws + 0);              //  8 MB
  f16*   XWt  = (f16*)(ws + 8388608);        //  4 MB
  f16*   Wt   = (f16*)(ws + 12582912);       // 64 KB
  float* n2   = (float*)(ws + 12648448);     // 64 KB
  float* Lp   = (float*)(ws + 12713984);     // <=1 MB
  float* Yp   = (float*)(ws + 13762560);     // <=32 MB (split-K=4 partials)
  const size_t P_off = 47316992;
  f16*   Pbuf = (f16*)(ws + P_off);

  int bpp = 1;
  if      (ws_size >= P_off + (size_t)8 * 2048 * 2048 * 2) bpp = 8;
  else if (ws_size >= P_off + (size_t)4 * 2048 * 2048 * 2) bpp = 4;
  else if (ws_size >= P_off + (size_t)2 * 2048 * 2048 * 2) bpp = 2;
  const int bsh = (bpp == 8) ? 3 : (bpp == 4) ? 2 : (bpp == 2) ? 1 : 0;
  const int bm = bpp - 1;
  const int kso = bpp * 2048;

  prep<<<288, 256, 0, stream>>>(x, Wm, Wl, xh, n2, Wt);
  xw_kern<<<256, 256, 0, stream>>>(xh, Wt, XWt);
  for (int b0 = 0; b0 < 8; b0 += bpp) {
    gemm1_kern<<<bpp * 136, 256, 0, stream>>>(xh, n2, Pbuf, Lp, b0, bm, bsh);
    gemm2p_kern<<<bpp * 64, 256, 0, stream>>>(Pbuf, XWt, Yp, b0, bm, bsh, kso);
    reduce_kern<<<bpp * 64, 256, 0, stream>>>(Yp, Lp, bmv, blv, ep, out, b0, kso);
  }
}

// Round 15
// 79.731 us; speedup vs baseline: 1.0042x; 1.0042x over previous
//
#include <hip/hip_runtime.h>

#define B_ 8
#define S_ 2048
#define D_ 256

typedef _Float16 f16;
typedef f16 f16x2 __attribute__((ext_vector_type(2)));
typedef f16 f16x8 __attribute__((ext_vector_type(8)));
typedef float f32x16 __attribute__((ext_vector_type(16)));
typedef unsigned int u32;
typedef u32 u32x4 __attribute__((ext_vector_type(4)));

typedef const __attribute__((address_space(1))) unsigned int* gptr_t;
typedef __attribute__((address_space(3))) unsigned int* lptr_t;

__device__ __forceinline__ void gload_lds16(const void* g, void* l) {
  __builtin_amdgcn_global_load_lds((gptr_t)(unsigned long long)g,
                                   (lptr_t)(unsigned long long)l, 16, 0, 0);
}

__device__ __forceinline__ u32 packf16(float a, float b) {
  f16x2 t; t[0] = (f16)a; t[1] = (f16)b;
  return __builtin_bit_cast(u32, t);
}

// acc (lane-dim col, crow rows) -> lane holds its lane-row, crow-contiguous:
// s0 = crow 0..15 (16B at +hi*8), s1 = crow 16..31 (+16+hi*8).
__device__ __forceinline__ void pack16(const f32x16& p, int hi, u32x4& o0, u32x4& o1) {
#pragma unroll
  for (int c2 = 0; c2 < 2; ++c2) {
    u32 a1 = packf16(p[8 * c2 + 0], p[8 * c2 + 1]);
    u32 a2 = packf16(p[8 * c2 + 2], p[8 * c2 + 3]);
    u32 b1 = packf16(p[8 * c2 + 4], p[8 * c2 + 5]);
    u32 b2 = packf16(p[8 * c2 + 6], p[8 * c2 + 7]);
    u32 xa1 = __shfl_xor(a1, 32), xa2 = __shfl_xor(a2, 32);
    u32 xb1 = __shfl_xor(b1, 32), xb2 = __shfl_xor(b2, 32);
    u32x4 f;
    f[0] = hi ? xb1 : a1;
    f[1] = hi ? xb2 : a2;
    f[2] = hi ? b1 : xa1;
    f[3] = hi ? b2 : xa2;
    if (c2) o1 = f; else o0 = f;
  }
}

#define SC2F 0.09016844f   // log2(e)/16
#define NMAXR 20.0f        // >= max row norm (chi2_256 max ~ sqrt(397))

// ---- fused prep: xh (f16), n2 (row norms^2), Wt[128 j][256 d] -------------
__global__ void prep(const float* __restrict__ x, const float* __restrict__ Wm,
                     const float* __restrict__ Wl, f16* __restrict__ xh,
                     float* __restrict__ n2, f16* __restrict__ Wt) {
  __shared__ f16 tile[64][264];
  const int bid = blockIdx.x;
  const int t = threadIdx.x;          // 256
  if (bid < 256) {
    const int b = bid >> 5, st = bid & 31;
    const int s0 = st * 64;
    const float* xb = x + ((size_t)(b * S_ + s0)) * D_;
    f16* xhb = xh + ((size_t)(b * S_ + s0)) * D_;
#pragma unroll
    for (int it = 0; it < 16; ++it) {
      int flat = it * 256 + t;
      int r = flat >> 6, c4 = flat & 63;
      float4 v = *reinterpret_cast<const float4*>(xb + r * 256 + c4 * 4);
      f16 h0 = (f16)v.x, h1 = (f16)v.y, h2 = (f16)v.z, h3 = (f16)v.w;
      f16x2 p0 = {h0, h1}, p1 = {h2, h3};
      uint2 wv; wv.x = __builtin_bit_cast(u32, p0); wv.y = __builtin_bit_cast(u32, p1);
      *reinterpret_cast<uint2*>(xhb + r * 256 + c4 * 4) = wv;
      tile[r][c4 * 4 + 0] = h0; tile[r][c4 * 4 + 1] = h1;
      tile[r][c4 * 4 + 2] = h2; tile[r][c4 * 4 + 3] = h3;
    }
    __syncthreads();
    {
      int r = t >> 2, qd = t & 3;
      float s = 0.0f;
#pragma unroll
      for (int i = 0; i < 8; ++i) {
        f16x8 v = *reinterpret_cast<const f16x8*>(&tile[r][qd * 64 + i * 8]);
#pragma unroll
        for (int u = 0; u < 8; ++u) { float f = (float)v[u]; s += f * f; }
      }
      s += __shfl_xor(s, 1); s += __shfl_xor(s, 2);
      if (qd == 0) n2[b * S_ + s0 + r] = s;
    }
  } else {
    int idx = (bid - 256) * 1024 + t * 4;
    int j = idx >> 8, d = idx & 255;
#pragma unroll
    for (int k2 = 0; k2 < 4; ++k2) {
      float v = (j < 64) ? Wm[(d + k2) * 64 + j] : Wl[(d + k2) * 64 + (j - 64)];
      Wt[idx + k2] = (f16)v;
    }
  }
}

// ---- xw: XWt[b][j 128][s 2048] = (xh @ Wt^T)^T, f16 -----------------------
__launch_bounds__(256)
__global__ void xw_kern(const f16* __restrict__ xh, const f16* __restrict__ Wt,
                        f16* __restrict__ XWt) {
  __shared__ f16 Ax[2][4096];   // [buf][64 s][64 d]
  __shared__ f16 Ww[2][8192];   // [buf][128 j][64 d]
  const int idx = blockIdx.x;
  const int b = idx & 7;
  const int sb = (idx >> 3) * 64;
  const int tid = threadIdx.x, lane = tid & 63, w = tid >> 6;   // w = wj
  const int l31 = lane & 31, hi = lane >> 5;
  const f16* xb = xh + (size_t)b * S_ * D_;

#define XW_STAGE(st, pp)                                                       \
  {                                                                            \
    _Pragma("unroll") for (int i = 0; i < 2; ++i) {                            \
      int ch = i * 256 + tid; int r = ch >> 3, c = ch & 7;                     \
      int csrc = c ^ (r & 7);                                                  \
      gload_lds16(xb + (size_t)(sb + r) * 256 + ((st) * 64) + csrc * 8,        \
                  &Ax[(pp)][0] + ch * 8);                                      \
    }                                                                          \
    _Pragma("unroll") for (int i = 0; i < 4; ++i) {                            \
      int ch = i * 256 + tid; int r = ch >> 3, c = ch & 7;                     \
      int csrc = c ^ (r & 7);                                                  \
      gload_lds16(Wt + (size_t)r * 256 + ((st) * 64) + csrc * 8,               \
                  &Ww[(pp)][0] + ch * 8);                                      \
    }                                                                          \
  }

  f32x16 acc[2];
#pragma unroll
  for (int i = 0; i < 2; ++i)
#pragma unroll
    for (int e = 0; e < 16; ++e) acc[i][e] = 0.0f;

  XW_STAGE(0, 0);
  __syncthreads();
#pragma unroll
  for (int t = 0; t < 4; ++t) {
    const int p = t & 1;
    if (t < 3) XW_STAGE(t + 1, p ^ 1);
#pragma unroll
    for (int kc = 0; kc < 4; ++kc) {
      int cc = ((2 * kc + hi) ^ (l31 & 7)) * 8;
      f16x8 bf = *reinterpret_cast<const f16x8*>(&Ww[p][(w * 32 + l31) * 64 + cc]);
#pragma unroll
      for (int mi = 0; mi < 2; ++mi) {
        f16x8 af = *reinterpret_cast<const f16x8*>(&Ax[p][(mi * 32 + l31) * 64 + cc]);
        acc[mi] = __builtin_amdgcn_mfma_f32_32x32x16_f16(af, bf, acc[mi], 0, 0, 0);
      }
    }
    __syncthreads();
  }
#undef XW_STAGE

  const int j = w * 32 + l31;
  f16* dst = XWt + ((size_t)b * 128 + j) * 2048;
#pragma unroll
  for (int mi = 0; mi < 2; ++mi) {
    u32x4 s0, s1;
    pack16(acc[mi], hi, s0, s1);
    *reinterpret_cast<u32x4*>(dst + sb + mi * 32 + hi * 8) = s0;
    *reinterpret_cast<u32x4*>(dst + sb + mi * 32 + 16 + hi * 8) = s1;
  }
}

// ------ GEMM1 (triangular): S-tile once, store P[q,kv] and P[kv,q], Lp -----
// (verbatim from R13 — passing, ~28 us)
__launch_bounds__(512, 4)
__global__ void gemm1_kern(const f16* __restrict__ xh, const float* __restrict__ n2,
                           f16* __restrict__ P, float* __restrict__ Lp,
                           int b0, int bm, int bsh) {
  __shared__ __align__(16) char smem[65536];
  f16* Aq = (f16*)smem;            // 2 bufs x [128 q][64 d]
  f16* Bk = (f16*)(smem + 32768);  // 2 bufs x [128 kv][64 d]
  const int idx = blockIdx.x;
  const int bl = idx & bm;
  int tdec = idx >> bsh;           // 0..135
  int qt = 0;
#pragma unroll 1
  while (tdec >= 16 - qt) { tdec -= 16 - qt; ++qt; }
  const int kt = qt + tdec;
  const int b = b0 + bl;
  const int qb = qt * 128, kb = kt * 128;
  const int tid = threadIdx.x, lane = tid & 63, w = tid >> 6;
  const int l31 = lane & 31, hi = lane >> 5;
  const int wq = w >> 2, wk = w & 3;
  const f16* xb = xh + (size_t)b * S_ * D_;

#define G1_STAGE(st, pp)                                                       \
  { _Pragma("unroll") for (int i = 0; i < 4; ++i) {                            \
      int ii = w * 4 + i;                                                      \
      int flat = ii * 64 + lane;                                               \
      bool isB = ii >= 16;                                                     \
      int ch = isB ? flat - 1024 : flat;                                       \
      int r = ch >> 3, c = ch & 7;                                             \
      int csrc = c ^ (r & 7);                                                  \
      const f16* src = xb + (size_t)((isB ? kb : qb) + r) * 256 +              \
                       (st) * 64 + csrc * 8;                                   \
      f16* dst = (isB ? Bk : Aq) + ((pp) * 8192) + ch * 8;                     \
      gload_lds16(src, dst);                                                   \
    } }

  f32x16 acc[2];
#pragma unroll
  for (int i = 0; i < 2; ++i)
#pragma unroll
    for (int e = 0; e < 16; ++e) acc[i][e] = 0.0f;

  G1_STAGE(0, 0);
  __syncthreads();
#pragma unroll
  for (int t = 0; t < 4; ++t) {
    const int p = t & 1;
    if (t < 3) G1_STAGE(t + 1, p ^ 1);
#pragma unroll
    for (int kc = 0; kc < 4; ++kc) {
      int cc = ((2 * kc + hi) ^ (l31 & 7)) * 8;
      f16x8 af  = *reinterpret_cast<const f16x8*>(Bk + p * 8192 + (wk * 32 + l31) * 64 + cc);
      f16x8 bf0 = *reinterpret_cast<const f16x8*>(Aq + p * 8192 + (wq * 64 + l31) * 64 + cc);
      f16x8 bf1 = *reinterpret_cast<const f16x8*>(Aq + p * 8192 + (wq * 64 + 32 + l31) * 64 + cc);
      acc[0] = __builtin_amdgcn_mfma_f32_32x32x16_f16(af, bf0, acc[0], 0, 0, 0);
      acc[1] = __builtin_amdgcn_mfma_f32_32x32x16_f16(af, bf1, acc[1], 0, 0, 0);
    }
    __syncthreads();
  }
#undef G1_STAGE

  float* raw = (float*)smem;   // [128 kv][128 q]
  if (kt != qt) {
#pragma unroll
    for (int ni = 0; ni < 2; ++ni)
#pragma unroll
      for (int j = 0; j < 16; ++j) {
        int kvloc = wk * 32 + (j & 3) + 8 * (j >> 2) + 4 * hi;
        int qloc = wq * 64 + ni * 32 + l31;
        raw[kvloc * 128 + (qloc ^ ((kvloc & 7) << 2))] = acc[ni][j];
      }
  }

  float r2[2], lsum[2];
  int qrow[2];
#pragma unroll
  for (int ni = 0; ni < 2; ++ni) {
    qrow[ni] = qb + wq * 64 + ni * 32 + l31;
    r2[ni] = sqrtf(n2[b * S_ + qrow[ni]]) * (NMAXR * SC2F);
    lsum[ni] = 0.0f;
  }
#pragma unroll
  for (int ni = 0; ni < 2; ++ni)
#pragma unroll
    for (int j = 0; j < 16; ++j) {
      float v = exp2f(acc[ni][j] * SC2F - r2[ni]);
      acc[ni][j] = v;
      lsum[ni] += v;
    }
#pragma unroll
  for (int ni = 0; ni < 2; ++ni) lsum[ni] += __shfl_xor(lsum[ni], 32);

  const int colb = kb + wk * 32;
#pragma unroll
  for (int ni = 0; ni < 2; ++ni) {
    u32x4 s0, s1;
    pack16(acc[ni], hi, s0, s1);
    size_t rowp = (size_t)(bl * S_ + qrow[ni]) * 2048;
    *reinterpret_cast<u32x4*>(P + rowp + colb + hi * 8) = s0;
    *reinterpret_cast<u32x4*>(P + rowp + colb + 16 + hi * 8) = s1;
  }

  if (kt != qt) {
    __syncthreads();
    const int kvr = tid >> 2;
    const int qseg = (tid & 3) * 32;
    float r2kv = sqrtf(n2[b * S_ + kb + kvr]) * (NMAXR * SC2F);
    u32 ow[16];
    float tsum = 0.0f;
#pragma unroll
    for (int c8 = 0; c8 < 8; ++c8) {
      int qs = qseg + c8 * 4;
      float4 v = *reinterpret_cast<const float4*>(
          &raw[kvr * 128 + (qs ^ ((kvr & 7) << 2))]);
      float e0 = exp2f(v.x * SC2F - r2kv), e1 = exp2f(v.y * SC2F - r2kv);
      float e2 = exp2f(v.z * SC2F - r2kv), e3 = exp2f(v.w * SC2F - r2kv);
      tsum += (e0 + e1) + (e2 + e3);
      ow[c8 * 2 + 0] = packf16(e0, e1);
      ow[c8 * 2 + 1] = packf16(e2, e3);
    }
    size_t rowp = (size_t)(bl * S_ + kb + kvr) * 2048;
#pragma unroll
    for (int sseg = 0; sseg < 4; ++sseg) {
      u32x4 sv;
      sv[0] = ow[sseg * 4 + 0]; sv[1] = ow[sseg * 4 + 1];
      sv[2] = ow[sseg * 4 + 2]; sv[3] = ow[sseg * 4 + 3];
      *reinterpret_cast<u32x4*>(P + rowp + qb + qseg + sseg * 8) = sv;
    }
    tsum += __shfl_xor(tsum, 1);
    tsum += __shfl_xor(tsum, 2);
    if ((tid & 3) == 0)
      Lp[(size_t)(bl * 16 + qt) * 2048 + kb + kvr] = tsum;
  }

  __syncthreads();
  float* Lred = (float*)smem;   // [128 q][4 wk]
  if (hi == 0) {
    Lred[(wq * 64 + l31) * 4 + wk] = lsum[0];
    Lred[(wq * 64 + 32 + l31) * 4 + wk] = lsum[1];
  }
  __syncthreads();
  if (tid < 128) {
    float s = Lred[tid * 4] + Lred[tid * 4 + 1] + Lred[tid * 4 + 2] + Lred[tid * 4 + 3];
    Lp[(size_t)(bl * 16 + kt) * 2048 + qb + tid] = s;
  }
}

// ------ GEMM2P (split-K=4): Yp[ks] = (P @ XWt^T)/L over K-quarter ----------
// tile 64q x 128j, K/4=512 in 8 steps of 64; grid bpp*128:
//   bl = idx & (bpp-1), qt = next 5 bits, ks = top 2 bits
// 4 waves (wq2 x wc2): wave 32q x paired cols {wc*32, 64+wc*32}, acc[2]
__launch_bounds__(256, 3)
__global__ void gemm2p_kern(const f16* __restrict__ P, const f16* __restrict__ XWt,
                            const float* __restrict__ Lp, float* __restrict__ Yp,
                            int b0, int bm_, int bsh, int kso) {
  __shared__ f16 Pq[2][4096];   // [buf][64 q][64 kv]
  __shared__ f16 Xw[2][8192];   // [buf][128 j][64 kv]
  const int idx = blockIdx.x;
  const int bl = idx & bm_;
  const int qt = (idx >> bsh) & 31;
  const int ks = idx >> (bsh + 5);   // 0..3
  const int b = b0 + bl;
  const int qb = qt * 64;
  const int kcol0 = ks * 512;
  const int tid = threadIdx.x, lane = tid & 63, w = tid >> 6;
  const int l31 = lane & 31, hi = lane >> 5;
  const int wq = w & 1, wc = w >> 1;
  const f16* xwb = XWt + (size_t)b * 128 * 2048;

#define GP_STAGE(tt, pp)                                                       \
  {                                                                            \
    _Pragma("unroll") for (int i = 0; i < 2; ++i) {                            \
      int ch = i * 256 + tid; int r = ch >> 3, c = ch & 7;                     \
      int csrc = c ^ (r & 7);                                                  \
      gload_lds16(P + (size_t)(bl * S_ + qb + r) * 2048 + kcol0 + ((tt) * 64) + csrc * 8, \
                  &Pq[(pp)][0] + ch * 8);                                      \
    }                                                                          \
    _Pragma("unroll") for (int i = 0; i < 4; ++i) {                            \
      int ch = i * 256 + tid; int r = ch >> 3, c = ch & 7;                     \
      int csrc = c ^ (r & 7);                                                  \
      gload_lds16(xwb + (size_t)r * 2048 + kcol0 + ((tt) * 64) + csrc * 8,     \
                  &Xw[(pp)][0] + ch * 8);                                      \
    }                                                                          \
  }

  f32x16 acc[2];
#pragma unroll
  for (int i = 0; i < 2; ++i)
#pragma unroll
    for (int e = 0; e < 16; ++e) acc[i][e] = 0.0f;

  GP_STAGE(0, 0);
  __syncthreads();
#pragma unroll 1
  for (int t = 0; t < 8; ++t) {
    const int p = t & 1;
    if (t < 7) GP_STAGE(t + 1, p ^ 1);
#pragma unroll
    for (int kc = 0; kc < 4; ++kc) {
      int cc = ((2 * kc + hi) ^ (l31 & 7)) * 8;
      f16x8 bf = *reinterpret_cast<const f16x8*>(&Pq[p][(wq * 32 + l31) * 64 + cc]);
#pragma unroll
      for (int mi = 0; mi < 2; ++mi) {
        int jrow = mi * 64 + wc * 32 + l31;
        f16x8 af = *reinterpret_cast<const f16x8*>(&Xw[p][jrow * 64 + cc]);
        acc[mi] = __builtin_amdgcn_mfma_f32_32x32x16_f16(af, bf, acc[mi], 0, 0, 0);
      }
    }
    __syncthreads();
  }
#undef GP_STAGE

  // epilogue: apply rL to partials, store f32
  const int q = qb + wq * 32 + l31;
  float L = 0.0f;
#pragma unroll
  for (int kt = 0; kt < 16; ++kt) L += Lp[(size_t)(bl * 16 + kt) * 2048 + q];
  float rL = 1.0f / L;
  float* dst = Yp + ((size_t)ks * kso + (size_t)bl * S_ + q) * 128;
#pragma unroll
  for (int jg = 0; jg < 4; ++jg) {
    int cb = wc * 32 + 8 * jg + 4 * hi;
    float4 mn, lv;
    float* mnp = &mn.x; float* lvp = &lv.x;
#pragma unroll
    for (int jj = 0; jj < 4; ++jj) {
      int j = jg * 4 + jj;
      mnp[jj] = acc[0][j] * rL;
      lvp[jj] = acc[1][j] * rL;
    }
    *reinterpret_cast<float4*>(dst + cb) = mn;
    *reinterpret_cast<float4*>(dst + 64 + cb) = lv;
  }
}

// ------ reduce: out = reparam( Yp0+Yp1+Yp2+Yp3 + bias ) --------------------
// grid bpp*64: block = 32 rows x 64 paired cols; thread = 1 row x 8 cols
__launch_bounds__(256)
__global__ void reduce_kern(const float* __restrict__ Yp, const float* __restrict__ bm,
                            const float* __restrict__ bl_, const float* __restrict__ eps,
                            float* __restrict__ out, int b0, int kso) {
  const int t = threadIdx.x;
  const int rowp = blockIdx.x * 32 + (t >> 3);
  const int j0 = (t & 7) * 8;
  const int grow = b0 * S_ + rowp;
  float mv[8], lv[8];
#pragma unroll
  for (int i = 0; i < 8; ++i) { mv[i] = 0.0f; lv[i] = 0.0f; }
#pragma unroll
  for (int k = 0; k < 4; ++k) {
    const float* y = Yp + ((size_t)k * kso + rowp) * 128;
#pragma unroll
    for (int i = 0; i < 2; ++i) {
      float4 a = *reinterpret_cast<const float4*>(y + j0 + i * 4);
      float4 c = *reinterpret_cast<const float4*>(y + 64 + j0 + i * 4);
      mv[i*4+0] += a.x; mv[i*4+1] += a.y; mv[i*4+2] += a.z; mv[i*4+3] += a.w;
      lv[i*4+0] += c.x; lv[i*4+1] += c.y; lv[i*4+2] += c.z; lv[i*4+3] += c.w;
    }
  }
  float ev[8];
#pragma unroll
  for (int i = 0; i < 2; ++i) {
    float4 e = *reinterpret_cast<const float4*>(eps + (size_t)grow * 64 + j0 + i * 4);
    ev[i*4+0] = e.x; ev[i*4+1] = e.y; ev[i*4+2] = e.z; ev[i*4+3] = e.w;
  }
  float om[8], ol[8], oa[8];
#pragma unroll
  for (int i = 0; i < 8; ++i) {
    float m = mv[i] + bm[j0 + i];
    float l = lv[i] + bl_[j0 + i];
    om[i] = m;
    ol[i] = l;
    oa[i] = m + exp2f(0.7213475204f * l) * ev[i];
  }
  float* o0 = out + (size_t)grow * 64 + j0;
#pragma unroll
  for (int i = 0; i < 2; ++i) {
    *reinterpret_cast<float4*>(o0 + i * 4) = *reinterpret_cast<float4*>(&om[i * 4]);
    *reinterpret_cast<float4*>(o0 + 1048576 + i * 4) = *reinterpret_cast<float4*>(&ol[i * 4]);
    *reinterpret_cast<float4*>(o0 + 2097152 + i * 4) = *reinterpret_cast<float4*>(&oa[i * 4]);
  }
}

extern "C" void kernel_launch(void* const* d_in, const int* in_sizes, int n_in,
                              void* d_out, int out_size, void* d_ws, size_t ws_size,
                              hipStream_t stream) {
  (void)in_sizes; (void)n_in; (void)out_size;
  const float* x   = (const float*)d_in[0];
  const float* Wm  = (const float*)d_in[1];
  const float* bmv = (const float*)d_in[2];
  const float* Wl  = (const float*)d_in[3];
  const float* blv = (const float*)d_in[4];
  const float* ep  = (const float*)d_in[5];
  float* out = (float*)d_out;

  char* ws = (char*)d_ws;
  f16*   xh   = (f16*)(ws + 0);              //  8 MB
  f16*   XWt  = (f16*)(ws + 8388608);        //  4 MB
  f16*   Wt   = (f16*)(ws + 12582912);       // 64 KB
  float* n2   = (float*)(ws + 12648448);     // 64 KB
  float* Lp   = (float*)(ws + 12713984);     // <=1 MB
  float* Yp   = (float*)(ws + 13762560);     // <=32 MB (split-K=4 partials)
  const size_t P_off = 47316992;
  f16*   Pbuf = (f16*)(ws + P_off);

  int bpp = 1;
  if      (ws_size >= P_off + (size_t)8 * 2048 * 2048 * 2) bpp = 8;
  else if (ws_size >= P_off + (size_t)4 * 2048 * 2048 * 2) bpp = 4;
  else if (ws_size >= P_off + (size_t)2 * 2048 * 2048 * 2) bpp = 2;
  const int bsh = (bpp == 8) ? 3 : (bpp == 4) ? 2 : (bpp == 2) ? 1 : 0;
  const int bm = bpp - 1;
  const int kso = bpp * 2048;

  prep<<<288, 256, 0, stream>>>(x, Wm, Wl, xh, n2, Wt);
  xw_kern<<<256, 256, 0, stream>>>(xh, Wt, XWt);
  for (int b0 = 0; b0 < 8; b0 += bpp) {
    gemm1_kern<<<bpp * 136, 512, 0, stream>>>(xh, n2, Pbuf, Lp, b0, bm, bsh);
    gemm2p_kern<<<bpp * 128, 256, 0, stream>>>(Pbuf, XWt, Lp, Yp, b0, bm, bsh, kso);
    reduce_kern<<<bpp * 64, 256, 0, stream>>>(Yp, bmv, blv, ep, out, b0, kso);
  }
}